// Round 5
// baseline (10.220 us; speedup 1.0000x reference)
//
#include <hip/hip_runtime.h>
#include <math.h>

#define TINY 1e-6f

// ---- DPP helpers (compile-time ctrl; CDNA/gfx9 DPP set) ----
template <int CTRL, int RM, int BM, bool BC>
__device__ __forceinline__ float updpp(float oldv, float x) {
    return __int_as_float(__builtin_amdgcn_update_dpp(
        __float_as_int(oldv), __float_as_int(x), CTRL, RM, BM, BC));
}

// row-local: lane i <- lane i+1 (row-last -> 0)
__device__ __forceinline__ float row_shl1(float x) {
    return updpp<0x101, 0xf, 0xf, true>(0.f, x);
}
// row-local: lane i <- lane i-1 (row-first -> oldv)
__device__ __forceinline__ float row_shr1(float x, float oldv) {
    return updpp<0x111, 0xf, 0xf, false>(oldv, x);
}

// 8-lane-segment inclusive ADD prefix scan. k1/k2/k4 are per-lane masks
// (0.0 where the shifted source would cross the 8-lane segment boundary).
__device__ __forceinline__ float sscan_add8(float x, float k1, float k2, float k4) {
    float t;
    t = updpp<0x111, 0xf, 0xf, true>(0.f, x); x = fmaf(t, k1, x);  // shr:1
    t = updpp<0x112, 0xf, 0xf, true>(0.f, x); x = fmaf(t, k2, x);  // shr:2
    t = updpp<0x114, 0xf, 0xf, true>(0.f, x); x = fmaf(t, k4, x);  // shr:4
    return x;
}

// 8-lane-segment inclusive MUL prefix scan (masked lanes multiply by 1).
__device__ __forceinline__ float sscan_mul8(float x, float k1, float q1,
                                            float k2, float q2,
                                            float k4, float q4) {
    float t;
    t = updpp<0x111, 0xf, 0xf, false>(1.f, x); x *= fmaf(t, k1, q1);
    t = updpp<0x112, 0xf, 0xf, false>(1.f, x); x *= fmaf(t, k2, q2);
    t = updpp<0x114, 0xf, 0xf, false>(1.f, x); x *= fmaf(t, k4, q4);
    return x;
}

// 8-lane-segment reduction-to-last-lane. NO masks needed: lane 7 sums
// x0..x7 trivially; lane 15 = s2[15]+s2[11] reads only lanes >= 8.
// Valid ONLY at row positions 7 and 15 (sl==7 of each segment).
__device__ __forceinline__ float sred_add8(float x) {
    x += updpp<0x111, 0xf, 0xf, true>(0.f, x);
    x += updpp<0x112, 0xf, 0xf, true>(0.f, x);
    x += updpp<0x114, 0xf, 0xf, true>(0.f, x);
    return x;
}

// 8 rays per 64-lane wave (8-lane segments), 16 samples per lane (N=128).
__global__ __launch_bounds__(64) void nerf_render_kernel(
    const float* __restrict__ ray_d,      // [R,3]
    const float* __restrict__ fg_z_max,   // [R]
    const float* __restrict__ z_vals,     // [R,128]
    const float* __restrict__ sigma,      // [R,128]
    const float* __restrict__ rgb,        // [R,128,3]
    const float* __restrict__ bg_rgb,     // [R,3]
    float* __restrict__ o_rgb_map,        // [R,3]
    float* __restrict__ o_weights,        // [R,128]
    float* __restrict__ o_fg_rgb,         // [R,3]
    float* __restrict__ o_depth,          // [R]
    float* __restrict__ o_bg_lambda,      // [R]
    float* __restrict__ o_ldist,          // [R]
    float* __restrict__ o_tv,             // [R]
    int R)
{
    const int lane = threadIdx.x;          // block = 1 wave
    const int sl   = lane & 7;             // lane within 8-lane segment
    const int ray  = blockIdx.x * 8 + (lane >> 3);
    if (ray >= R) return;

    const int base = ray * 128 + 16 * sl;  // first of this lane's 16 samples

    // ---- issue ALL loads up front (20 aligned dwordx4 + per-ray scalars) ----
    const float4 za = *reinterpret_cast<const float4*>(z_vals + base + 0);
    const float4 zc = *reinterpret_cast<const float4*>(z_vals + base + 4);
    const float4 ze = *reinterpret_cast<const float4*>(z_vals + base + 8);
    const float4 zg = *reinterpret_cast<const float4*>(z_vals + base + 12);
    const float4 s0 = *reinterpret_cast<const float4*>(sigma + base + 0);
    const float4 s1 = *reinterpret_cast<const float4*>(sigma + base + 4);
    const float4 s2 = *reinterpret_cast<const float4*>(sigma + base + 8);
    const float4 s3 = *reinterpret_cast<const float4*>(sigma + base + 12);
    const float* rp = rgb + (long)base * 3;   // 192 B, 16-aligned
    float4 c[12];
    #pragma unroll
    for (int i = 0; i < 12; ++i)
        c[i] = *reinterpret_cast<const float4*>(rp + 4 * i);
    const float zmax = fg_z_max[ray];
    const float dxv = ray_d[ray * 3 + 0];
    const float dyv = ray_d[ray * 3 + 1];
    const float dzv = ray_d[ray * 3 + 2];
    const float bgr = bg_rgb[ray * 3 + 0];
    const float bgg = bg_rgb[ray * 3 + 1];
    const float bgb = bg_rgb[ray * 3 + 2];

    // ---- segment-boundary masks for prefix scans (row pos 8..11 cases) ----
    const int rp16 = lane & 15;
    const float k1 = (rp16 == 8) ? 0.f : 1.f;
    const float k2 = (rp16 == 8 || rp16 == 9) ? 0.f : 1.f;
    const float k4 = (rp16 >= 8 && rp16 <= 11) ? 0.f : 1.f;
    const float q1 = 1.f - k1, q2 = 1.f - k2, q4 = 1.f - k4;

    const float nrm  = sqrtf(dxv * dxv + dyv * dyv + dzv * dzv);
    const float nrmh = 0.5f * nrm;

    float z[17];
    z[0]=za.x; z[1]=za.y; z[2]=za.z; z[3]=za.w;
    z[4]=zc.x; z[5]=zc.y; z[6]=zc.z; z[7]=zc.w;
    z[8]=ze.x; z[9]=ze.y; z[10]=ze.z; z[11]=ze.w;
    z[12]=zg.x; z[13]=zg.y; z[14]=zg.z; z[15]=zg.w;
    const float znext = row_shl1(z[0]);    // next lane's first z (row-local)
    z[16] = (sl == 7) ? zmax : znext;      // segment-last: close with z_max

    float sig[16];
    sig[0]=s0.x; sig[1]=s0.y; sig[2]=s0.z; sig[3]=s0.w;
    sig[4]=s1.x; sig[5]=s1.y; sig[6]=s1.z; sig[7]=s1.w;
    sig[8]=s2.x; sig[9]=s2.y; sig[10]=s2.z; sig[11]=s2.w;
    sig[12]=s3.x; sig[13]=s3.y; sig[14]=s3.z; sig[15]=s3.w;

    float d[16], m[16], e[16], f[16];
    #pragma unroll
    for (int i = 0; i < 16; ++i) {
        d[i] = (z[i + 1] - z[i]) * nrm;
        m[i] = (z[i] + z[i + 1]) * nrmh;
        e[i] = __expf(-sig[i] * d[i]);
        f[i] = e[i] + TINY;
    }

    // ---- segmented multiplicative scan over per-lane 16-products ----
    float oct = f[0];
    #pragma unroll
    for (int i = 1; i < 16; ++i) oct *= f[i];
    const float xincl = sscan_mul8(oct, k1, q1, k2, q2, k4, q4);
    const float bg_lambda = xincl;               // valid at sl==7
    float excl = row_shr1(xincl, 1.0f);          // row pos 0 -> 1.0
    excl = (sl == 0) ? 1.0f : excl;              // row pos 8 -> 1.0

    float w[16];
    {
        float T = excl;
        #pragma unroll
        for (int i = 0; i < 16; ++i) {
            w[i] = (1.0f - e[i]) * T;
            T *= f[i];
        }
    }

    // ---- stores of weights (issue early) ----
    *reinterpret_cast<float4*>(o_weights + base + 0)  = make_float4(w[0], w[1], w[2], w[3]);
    *reinterpret_cast<float4*>(o_weights + base + 4)  = make_float4(w[4], w[5], w[6], w[7]);
    *reinterpret_cast<float4*>(o_weights + base + 8)  = make_float4(w[8], w[9], w[10], w[11]);
    *reinterpret_cast<float4*>(o_weights + base + 12) = make_float4(w[12], w[13], w[14], w[15]);

    // ---- rgb / depth partials (frees the 48 colour regs early) ----
    float cr = 0.f, cg = 0.f, cb = 0.f, dep = 0.f;
    #pragma unroll
    for (int i = 0; i < 16; ++i) {
        const float* cc = reinterpret_cast<const float*>(c);
        cr  += w[i] * cc[3 * i + 0];
        cg  += w[i] * cc[3 * i + 1];
        cb  += w[i] * cc[3 * i + 2];
        dep += w[i] * z[i];                      // unscaled z
    }

    // ---- additive prefix scans for ldist ----
    float sw = 0.f, swm = 0.f;
    #pragma unroll
    for (int i = 0; i < 16; ++i) { sw += w[i]; swm += w[i] * m[i]; }
    const float xs = sscan_add8(sw,  k1, k2, k4);
    const float xm = sscan_add8(swm, k1, k2, k4);

    float cw  = xs - sw;                         // Σ w over samples before lane
    float cwm = xm - swm;
    float ld2 = 0.f, ld3 = 0.f;
    #pragma unroll
    for (int i = 0; i < 16; ++i) {
        ld2 += w[i] * (m[i] * cw - cwm);
        ld3 += w[i] * w[i] * d[i];
        cw  += w[i];
        cwm += w[i] * m[i];
    }
    float ldist = 2.0f * ld2 + ld3 * (1.0f / 3.0f);

    // ---- TV ----
    const float w0next = row_shl1(w[0]);         // cross-segment masked below
    float tv = 0.f;
    #pragma unroll
    for (int i = 1; i < 16; ++i) tv += fabsf(w[i] - w[i - 1]);
    tv += (sl < 7) ? fabsf(w0next - w[15]) : 0.0f;

    // ---- segmented reductions (totals at sl==7; maskless, see sred_add8) ----
    cr    = sred_add8(cr);
    cg    = sred_add8(cg);
    cb    = sred_add8(cb);
    dep   = sred_add8(dep);
    ldist = sred_add8(ldist);
    tv    = sred_add8(tv);

    if (sl == 7) {
        o_rgb_map[ray * 3 + 0] = cr + bg_lambda * bgr;
        o_rgb_map[ray * 3 + 1] = cg + bg_lambda * bgg;
        o_rgb_map[ray * 3 + 2] = cb + bg_lambda * bgb;
        o_fg_rgb[ray * 3 + 0] = cr;
        o_fg_rgb[ray * 3 + 1] = cg;
        o_fg_rgb[ray * 3 + 2] = cb;
        o_depth[ray]     = dep;
        o_bg_lambda[ray] = bg_lambda;
        o_ldist[ray]     = ldist;
        o_tv[ray]        = tv;
    }
}

extern "C" void kernel_launch(void* const* d_in, const int* in_sizes, int n_in,
                              void* d_out, int out_size, void* d_ws, size_t ws_size,
                              hipStream_t stream) {
    const float* ray_d   = (const float*)d_in[0];
    const float* fg_zmax = (const float*)d_in[1];
    const float* z_vals  = (const float*)d_in[2];
    const float* sigma   = (const float*)d_in[3];
    const float* rgb     = (const float*)d_in[4];
    const float* bg_rgb  = (const float*)d_in[5];

    const int R = in_sizes[1];          // fg_z_max: [R]

    float* out = (float*)d_out;
    float* o_rgb_map   = out;                       // R*3
    float* o_weights   = o_rgb_map + (long)R * 3;   // R*128
    float* o_fg_rgb    = o_weights + (long)R * 128; // R*3
    float* o_depth     = o_fg_rgb + (long)R * 3;    // R
    float* o_bg_lambda = o_depth + R;               // R
    float* o_ldist     = o_bg_lambda + R;           // R
    float* o_tv        = o_ldist + R;               // R

    // 8 rays per wave, 1 wave per block -> 1024 blocks (4 per CU)
    const int rays_per_block = 8;
    const int grid = (R + rays_per_block - 1) / rays_per_block;
    nerf_render_kernel<<<grid, 64, 0, stream>>>(
        ray_d, fg_zmax, z_vals, sigma, rgb, bg_rgb,
        o_rgb_map, o_weights, o_fg_rgb, o_depth, o_bg_lambda, o_ldist, o_tv, R);
}

// Round 6
// 9.866 us; speedup vs baseline: 1.0359x; 1.0359x over previous
//
#include <hip/hip_runtime.h>
#include <math.h>

#define TINY 1e-6f

// ---- DPP helpers (compile-time ctrl; CDNA/gfx9 DPP set) ----
template <int CTRL, int RM, int BM, bool BC>
__device__ __forceinline__ float updpp(float oldv, float x) {
    return __int_as_float(__builtin_amdgcn_update_dpp(
        __float_as_int(oldv), __float_as_int(x), CTRL, RM, BM, BC));
}

// 32-lane SEGMENTED inclusive add-scan (5 DPP steps, rows 0-31 / 32-63
// independent: row_shr never crosses 16-lane rows; row_bcast15 with
// row_mask 0xa only feeds lane15->row1 and lane47->row3).
__device__ __forceinline__ float scan_add32(float x) {
    x += updpp<0x111, 0xf, 0xf, true>(0.f, x);   // row_shr:1
    x += updpp<0x112, 0xf, 0xf, true>(0.f, x);   // row_shr:2
    x += updpp<0x114, 0xf, 0xf, true>(0.f, x);   // row_shr:4
    x += updpp<0x118, 0xf, 0xf, true>(0.f, x);   // row_shr:8
    x += updpp<0x142, 0xa, 0xf, true>(0.f, x);   // row_bcast15 -> rows 1,3
    return x;
}

// 32-lane segmented inclusive multiply-scan (identity via oldv=1, BC=0).
__device__ __forceinline__ float scan_mul32(float x) {
    x *= updpp<0x111, 0xf, 0xf, false>(1.f, x);
    x *= updpp<0x112, 0xf, 0xf, false>(1.f, x);
    x *= updpp<0x114, 0xf, 0xf, false>(1.f, x);
    x *= updpp<0x118, 0xf, 0xf, false>(1.f, x);
    x *= updpp<0x142, 0xa, 0xf, false>(1.f, x);
    return x;
}

// whole-wave lane shifts (cross the 32-boundary; callers mask there)
__device__ __forceinline__ float wave_shr1(float x, float oldv) {
    return updpp<0x138, 0xf, 0xf, false>(oldv, x);
}
__device__ __forceinline__ float wave_shl1(float x) {
    return updpp<0x130, 0xf, 0xf, true>(0.f, x);
}

// 2 rays per 64-lane wave (32-lane segments), 4 samples per lane (N=128).
// 4096 waves total -> 4 waves/SIMD; all scalar/tail loads hoisted to top.
__global__ __launch_bounds__(256, 4) void nerf_render_kernel(
    const float* __restrict__ ray_d,      // [R,3]
    const float* __restrict__ fg_z_max,   // [R]
    const float* __restrict__ z_vals,     // [R,128]
    const float* __restrict__ sigma,      // [R,128]
    const float* __restrict__ rgb,        // [R,128,3]
    const float* __restrict__ bg_rgb,     // [R,3]
    float* __restrict__ o_rgb_map,        // [R,3]
    float* __restrict__ o_weights,        // [R,128]
    float* __restrict__ o_fg_rgb,         // [R,3]
    float* __restrict__ o_depth,          // [R]
    float* __restrict__ o_bg_lambda,      // [R]
    float* __restrict__ o_ldist,          // [R]
    float* __restrict__ o_tv,             // [R]
    int R)
{
    const int lane = threadIdx.x & 63;
    const int wave = threadIdx.x >> 6;
    const int sl   = lane & 31;            // lane within segment (ray)
    const int ray  = (blockIdx.x * (blockDim.x >> 6) + wave) * 2 + (lane >> 5);
    if (ray >= R) return;

    const int base = ray * 128 + 4 * sl;   // first of this lane's 4 samples

    // ---- critical-path loads first: z, sigma, ray scalars ----
    const float4 zz = *reinterpret_cast<const float4*>(z_vals + base);
    const float4 sg = *reinterpret_cast<const float4*>(sigma  + base);
    const float zmax = fg_z_max[ray];
    const float dxv = ray_d[ray * 3 + 0];
    const float dyv = ray_d[ray * 3 + 1];
    const float dzv = ray_d[ray * 3 + 2];
    // tail-use loads issued up front too (hide their latency under compute)
    const float bgr = bg_rgb[ray * 3 + 0];
    const float bgg = bg_rgb[ray * 3 + 1];
    const float bgb = bg_rgb[ray * 3 + 2];
    // rgb last: consumed only after weights exist
    const float* rp = rgb + (long)base * 3;                 // 48B, 16-aligned
    const float4 v0 = *reinterpret_cast<const float4*>(rp + 0);
    const float4 v1 = *reinterpret_cast<const float4*>(rp + 4);
    const float4 v2 = *reinterpret_cast<const float4*>(rp + 8);

    const float nrm = sqrtf(dxv * dxv + dyv * dyv + dzv * dzv);

    // z after this lane's last sample: next lane's z0; segment-last: zmax
    const float znext = wave_shl1(zz.x);
    const float zb = (sl == 31) ? zmax : znext;

    const float d0 = (zz.y - zz.x) * nrm;
    const float d1 = (zz.z - zz.y) * nrm;
    const float d2 = (zz.w - zz.z) * nrm;
    const float d3 = (zb   - zz.w) * nrm;
    const float m0 = 0.5f * (zz.x + zz.y) * nrm;
    const float m1 = 0.5f * (zz.y + zz.z) * nrm;
    const float m2 = 0.5f * (zz.z + zz.w) * nrm;
    const float m3 = 0.5f * (zz.w + zb  ) * nrm;

    const float e0 = __expf(-sg.x * d0);
    const float e1 = __expf(-sg.y * d1);
    const float e2 = __expf(-sg.z * d2);
    const float e3 = __expf(-sg.w * d3);
    const float f0 = e0 + TINY, f1 = e1 + TINY, f2 = e2 + TINY, f3 = e3 + TINY;

    // ---- segmented multiplicative scan over per-lane quad products ----
    const float quad = (f0 * f1) * (f2 * f3);
    const float xincl = scan_mul32(quad);
    const float bg_lambda = xincl;               // valid at sl==31
    float excl = wave_shr1(xincl, 1.0f);         // lane32 gets rayA total...
    excl = (sl == 0) ? 1.0f : excl;              // ...masked here

    const float T0 = excl;
    const float T1 = T0 * f0;
    const float T2 = T1 * f1;
    const float T3 = T2 * f2;
    const float w0 = (1.0f - e0) * T0;
    const float w1 = (1.0f - e1) * T1;
    const float w2 = (1.0f - e2) * T2;
    const float w3 = (1.0f - e3) * T3;

    // ---- store weights early (no dependents) ----
    *reinterpret_cast<float4*>(o_weights + base) = make_float4(w0, w1, w2, w3);

    // ---- additive scans for ldist prefixes ----
    const float sw  = ((w0 + w1) + (w2 + w3));
    const float swm = (w0 * m0 + w1 * m1) + (w2 * m2 + w3 * m3);
    const float xs = scan_add32(sw);
    const float xm = scan_add32(swm);
    const float exw  = xs - sw;
    const float exwm = xm - swm;

    const float cw0 = exw,           cwm0 = exwm;
    const float cw1 = cw0 + w0,      cwm1 = cwm0 + w0 * m0;
    const float cw2 = cw1 + w1,      cwm2 = cwm1 + w1 * m1;
    const float cw3 = cw2 + w2,      cwm3 = cwm2 + w2 * m2;

    float ldist = 2.0f * (w0 * (m0 * cw0 - cwm0) + w1 * (m1 * cw1 - cwm1)
                        + w2 * (m2 * cw2 - cwm2) + w3 * (m3 * cw3 - cwm3))
                + ((w0 * w0 * d0 + w1 * w1 * d1)
                 + (w2 * w2 * d2 + w3 * w3 * d3)) * (1.0f / 3.0f);

    // ---- TV ----
    const float w0next = wave_shl1(w0);          // cross-boundary masked below
    float tv = fabsf(w1 - w0) + fabsf(w2 - w1) + fabsf(w3 - w2)
             + ((sl < 31) ? fabsf(w0next - w3) : 0.0f);

    // ---- rgb / depth partials ----
    float cr = (w0 * v0.x + w1 * v0.w) + (w2 * v1.z + w3 * v2.y);
    float cg = (w0 * v0.y + w1 * v1.x) + (w2 * v1.w + w3 * v2.z);
    float cb = (w0 * v0.z + w1 * v1.y) + (w2 * v2.x + w3 * v2.w);
    float dep = (w0 * zz.x + w1 * zz.y) + (w2 * zz.z + w3 * zz.w);  // unscaled z

    // ---- segmented reductions (totals land at sl==31) ----
    cr    = scan_add32(cr);
    cg    = scan_add32(cg);
    cb    = scan_add32(cb);
    dep   = scan_add32(dep);
    ldist = scan_add32(ldist);
    tv    = scan_add32(tv);

    if (sl == 31) {
        o_rgb_map[ray * 3 + 0] = cr + bg_lambda * bgr;
        o_rgb_map[ray * 3 + 1] = cg + bg_lambda * bgg;
        o_rgb_map[ray * 3 + 2] = cb + bg_lambda * bgb;
        o_fg_rgb[ray * 3 + 0] = cr;
        o_fg_rgb[ray * 3 + 1] = cg;
        o_fg_rgb[ray * 3 + 2] = cb;
        o_depth[ray]     = dep;
        o_bg_lambda[ray] = bg_lambda;
        o_ldist[ray]     = ldist;
        o_tv[ray]        = tv;
    }
}

extern "C" void kernel_launch(void* const* d_in, const int* in_sizes, int n_in,
                              void* d_out, int out_size, void* d_ws, size_t ws_size,
                              hipStream_t stream) {
    const float* ray_d   = (const float*)d_in[0];
    const float* fg_zmax = (const float*)d_in[1];
    const float* z_vals  = (const float*)d_in[2];
    const float* sigma   = (const float*)d_in[3];
    const float* rgb     = (const float*)d_in[4];
    const float* bg_rgb  = (const float*)d_in[5];

    const int R = in_sizes[1];          // fg_z_max: [R]

    float* out = (float*)d_out;
    float* o_rgb_map   = out;                       // R*3
    float* o_weights   = o_rgb_map + (long)R * 3;   // R*128
    float* o_fg_rgb    = o_weights + (long)R * 128; // R*3
    float* o_depth     = o_fg_rgb + (long)R * 3;    // R
    float* o_bg_lambda = o_depth + R;               // R
    float* o_ldist     = o_bg_lambda + R;           // R
    float* o_tv        = o_ldist + R;               // R

    // 2 rays per wave, 4 waves per block -> 8 rays per block, 1024 blocks
    const int rays_per_block = 8;
    const int grid = (R + rays_per_block - 1) / rays_per_block;
    nerf_render_kernel<<<grid, 256, 0, stream>>>(
        ray_d, fg_zmax, z_vals, sigma, rgb, bg_rgb,
        o_rgb_map, o_weights, o_fg_rgb, o_depth, o_bg_lambda, o_ldist, o_tv, R);
}